// Round 18
// baseline (404.935 us; speedup 1.0000x reference)
//
#include <hip/hip_runtime.h>
#include <hip/hip_bf16.h>
#include <stdint.h>

typedef __hip_bfloat16 bf;
typedef __attribute__((ext_vector_type(8))) short short8;
typedef __attribute__((ext_vector_type(4))) short short4v;
typedef __attribute__((ext_vector_type(4))) float float4v;
typedef __attribute__((ext_vector_type(2))) unsigned int uint2v;
__device__ __forceinline__ float b2f(bf x){ return __bfloat162float(x); }
__device__ __forceinline__ float s2f(short s){ union{ short s_; bf b_; } u; u.s_ = s; return b2f(u.b_); }
__device__ __forceinline__ float sane(float x){ return fminf(fmaxf(x, -1e6f), 1e6f); }

// Problem constants
constexpr int N   = 6144;          // NOT a power of two (3*2^11)!
constexpr int D   = 64;
constexpr int FE  = 32;
constexpr int Eg  = 196608;        // < 2^18 -> edge id packs in 18 bits; 768*256 == Eg
constexpr size_t NF = (size_t)N * D;
constexpr float LOG2E = 1.44269504088896340736f;
// Degrees ~ Poisson(32). P(deg > 96) ~ 1e-18/node -> fixed-capacity buckets.
constexpr int PAYC = 96;

__device__ __forceinline__ int clampi(int v){ return v < 0 ? 0 : (v >= N ? N - 1 : v); }
__device__ __forceinline__ float ldf(const void* p, size_t i, uint32_t isf32){
    return isf32 ? ((const float*)p)[i] : b2f(((const bf*)p)[i]);
}

// ---- float workspace layout (floats) ----  ~39 MB
constexpr size_t OF_OP   = 0;                           // [8][2][N][D]
constexpr size_t OF_LP   = OF_OP + 16*NF;               // [8][2][N]
constexpr size_t OF_MEAN = OF_LP + 16*(size_t)N;        // [2][N][D]
constexpr size_t OF_POOL = OF_MEAN + 2*NF;              // [4][N][FE]
constexpr size_t OF_QKVB = OF_POOL + (size_t)4*N*FE;    // bf16 [2][3][N][D] (Q pre-scaled)
constexpr size_t OF_WO   = OF_QKVB + 3*NF;              // [2][64][64] Wo_p, Wo_n
constexpr size_t OF_BO   = OF_WO + 8192;                // [2][64]
constexpr size_t OF_WF   = OF_BO + 128;                 // [384][64] final weight
constexpr size_t OF_BF   = OF_WF + 24576;               // [64]
constexpr size_t OF_O    = OF_BF + 64;                  // [2][N][D] FINAL attn numerator (corr-reduced)
constexpr size_t OF_L    = OF_O + 2*NF;                 // [2][N]    FINAL attn denominator
constexpr size_t F_TOTAL = OF_L + 2*(size_t)N;
// ---- u32 workspace (words, after float region) ----  ~9.5 MB
constexpr size_t OI_CUR  = 0;                           // [4][N] bucket counters
constexpr size_t OI_PAY  = OI_CUR + 4*(size_t)N;        // [4][N][PAYC] payload: e | (other<<18)
constexpr size_t OI_FLAG = OI_PAY + 4*(size_t)N*PAYC;   // [4] dtype flags

// per-wave dtype sniff, no sync needed: all lanes end with identical flag.
__device__ __forceinline__ uint32_t wave_sniff(const void* p){
    const bf* q = (const bf*)p;
    int lane = threadIdx.x & 63;
    float m = 0.f;
    #pragma unroll
    for (int k = 0; k < 4; ++k){
        float v = fabsf(b2f(q[lane + 64*k]));
        if (!(v <= 1e9f)) v = 1e9f;
        m = fmaxf(m, v);
    }
    m = fmaxf(m, __shfl_xor(m, 32, 64));
    m = fmaxf(m, __shfl_xor(m, 16, 64));
    m = fmaxf(m, __shfl_xor(m, 8, 64));
    m = fmaxf(m, __shfl_xor(m, 4, 64));
    m = fmaxf(m, __shfl_xor(m, 2, 64));
    m = fmaxf(m, __shfl_xor(m, 1, 64));
    return (m > 100.f) ? 1u : 0u;
}

// ---- K1: QKV GEMV from RAW inputs || Wo/final-W staging || flags ||
// counter-zero (replaces the memset launch; fill runs in K2 -> ordering safe).
__global__ void qkv_stage_kernel(const void* x1, const void* x2,
                                 const void* W0, const void* W1, const void* W2,
                                 const void* W3, const void* W4, const void* W5,
                                 const void* B0, const void* B1, const void* B2,
                                 const void* B3, const void* B4, const void* B5,
                                 const void* Wop, const void* bop,
                                 const void* Won, const void* bon,
                                 const void* wgt, const void* bia,
                                 const void* efp,
                                 uint32_t* __restrict__ iws, float* __restrict__ ws){
    int b = blockIdx.x, t = threadIdx.x;
    if (b < 9216){                           // ---- QKV GEMV from raw inputs ----
        int m = b / 1536;
        int wid = t >> 6, lane = t & 63;
        int i = (b % 1536) * 4 + wid;
        const void* xr = (m < 3) ? x1 : x2;
        const void* Wr = (m==0)?W0:(m==1)?W1:(m==2)?W2:(m==3)?W3:(m==4)?W4:W5;
        const void* Br = (m==0)?B0:(m==1)?B1:(m==2)?B2:(m==3)?B3:(m==4)?B4:B5;
        uint32_t fA = wave_sniff(xr);
        uint32_t fD = wave_sniff(W0);
        float xreg = sane(ldf(xr, (size_t)i * 64 + lane, fA));
        float acc;
        if (fD){                             // wave-uniform: typed f32 path
            const float* W = (const float*)Wr;
            acc = sane(((const float*)Br)[lane]);
            #pragma unroll 16
            for (int d = 0; d < 64; ++d)
                acc += __shfl(xreg, d, 64) * sane(W[d * 64 + lane]);
        } else {                             // typed bf16 path
            const bf* W = (const bf*)Wr;
            acc = sane(b2f(((const bf*)Br)[lane]));
            #pragma unroll 16
            for (int d = 0; d < 64; ++d)
                acc += __shfl(xreg, d, 64) * sane(b2f(W[d * 64 + lane]));
        }
        acc = sane(acc);
        if (m == 0 || m == 3) acc *= (0.125f * LOG2E);   // fold softmax scale AND log2e into Q
        bf* qkvb = (bf*)(ws + OF_QKVB);
        qkvb[(size_t)m * NF + (size_t)i * 64 + lane] = __float2bfloat16(acc);
        return;
    }
    b -= 9216;
    if (b < 129){                            // ---- Wo/bo + final W/b staging ----
        size_t idx = (size_t)b * 256 + t;
        uint32_t fD = wave_sniff(Wop);       // sniff BEFORE any early return (wave uniform)
        uint32_t fC = wave_sniff(wgt);
        if (idx >= 32960) return;
        if (idx < 8192){
            int k = (int)(idx >> 12), sub = (int)(idx & 4095);
            ws[OF_WO + idx] = sane(ldf(k ? Won : Wop, sub, fD));
        } else if (idx < 8320){
            int k = (int)((idx - 8192) >> 6), sub = (int)(idx & 63);
            ws[OF_BO + (idx - 8192)] = sane(ldf(k ? bon : bop, sub, fD));
        } else if (idx < 32896){
            ws[OF_WF + (idx - 8320)] = sane(ldf(wgt, idx - 8320, fC));
        } else {
            ws[OF_BF + (idx - 32896)] = sane(ldf(bia, idx - 32896, fC));
        }
        return;
    }
    if (b == 129){                           // ---- flags block (x fA, pool fB, final) ----
        __shared__ float red[256];
        uint32_t* flags = iws + OI_FLAG;
        const void* ps[4] = {x1, efp, wgt, W0};
        for (int k = 0; k < 4; ++k){
            const bf* p = (const bf*)ps[k];
            float m = 0.f;
            for (int i = t; i < 1024; i += 256){
                float v = fabsf(b2f(p[i]));
                if (!(v <= 1e9f)) v = 1e9f;
                m = fmaxf(m, v);
            }
            red[t] = m; __syncthreads();
            for (int off = 128; off; off >>= 1){
                if (t < off) red[t] = fmaxf(red[t], red[t + off]);
                __syncthreads();
            }
            if (t == 0) flags[k] = (red[0] > 100.f) ? 1u : 0u;
            __syncthreads();
        }
        return;
    }
    {                                        // ---- zero bucket counters (96 blocks) ----
        int z = (b - 130) * 256 + t;         // 96*256 == 4*N exactly
        iws[OI_CUR + z] = 0u;
    }
}

// ---- attn role (R18): each block owns 128 ROWS (two 64-row sets) x one
// column strip. K/V staging per tile is unchanged but serves 2x the MFMA
// work: QK runs per row set (A-frags re-read from LDS, cheap); PV reuses
// each Va fragment for both row sets. Staging cost per unit work halves.
// 768 blocks = 8 strips x 48 row-pairs x 2 signs.
__device__ __forceinline__ void attn_role(int b, short* __restrict__ Kl,
                                          short* __restrict__ Vl,
                                          short (* __restrict__ Pls)[16 * 40],
                                          const float* __restrict__ ws_ro,
                                          float* __restrict__ ws){
    constexpr int KP = 72;
    constexpr int VP = 72;
    constexpr int PPs = 40;
    const bf* qkvb = (const bf*)(ws_ro + OF_QKVB);

    int tid = threadIdx.x, lane = tid & 63, wv = tid >> 6;
    int m16 = lane & 15, quad = lane >> 4;
    int rp = b % 48, cs = (b / 48) & 7, sg = b / 384;
    const bf* Qb = qkvb + (size_t)(sg * 3) * NF;
    const bf* Kb = Qb + NF;
    const bf* Vb = Kb + NF;

    int rowA = rp * 128 + wv * 16;           // row set A
    int rowB = rowA + 64;                    // row set B
    short8 QA0 = *(const short8*)(Qb + (size_t)(rowA + m16) * 64 + quad * 8);
    short8 QA1 = *(const short8*)(Qb + (size_t)(rowA + m16) * 64 + 32 + quad * 8);
    short8 QB0 = *(const short8*)(Qb + (size_t)(rowB + m16) * 64 + quad * 8);
    short8 QB1 = *(const short8*)(Qb + (size_t)(rowB + m16) * 64 + 32 + quad * 8);

    float4v OcA[4], OcB[4];
    #pragma unroll
    for (int t = 0; t < 4; ++t){
        OcA[t] = (float4v){0.f, 0.f, 0.f, 0.f};
        OcB[t] = (float4v){0.f, 0.f, 0.f, 0.f};
    }
    float lA = 0.f, lB = 0.f;

    int scol = tid & 63, sgrp = tid >> 6;
    int c0 = cs * (N / 8), c1 = c0 + N / 8;  // 12 tiles of 64
    for (int cb = c0; cb < c1; cb += 64){
        {
            const short* ksrc = (const short*)(Kb + (size_t)(cb + scol) * 64 + sgrp * 16);
            *(short8*)(&Kl[scol * KP + sgrp * 16])     = *(const short8*)(ksrc);
            *(short8*)(&Kl[scol * KP + sgrp * 16 + 8]) = *(const short8*)(ksrc + 8);
            const short* vsrc = (const short*)(Vb + (size_t)(cb + scol) * 64 + sgrp * 16);
            short8 v0 = *(const short8*)(vsrc);
            short8 v1 = *(const short8*)(vsrc + 8);
            #pragma unroll
            for (int j = 0; j < 8; ++j) Vl[(sgrp * 16 + j) * VP + scol] = v0[j];
            #pragma unroll
            for (int j = 0; j < 8; ++j) Vl[(sgrp * 16 + 8 + j) * VP + scol] = v1[j];
        }
        __syncthreads();

        short* Pw = Pls[wv];
        #pragma unroll
        for (int kg = 0; kg < 2; ++kg){
            // ---- pass A: QK + exp for row set A ----
            #pragma unroll
            for (int ct = 0; ct < 2; ++ct){
                int colt = kg * 32 + ct * 16;
                short8 A0 = *(const short8*)(&Kl[(colt + m16) * KP + quad * 8]);
                short8 A1 = *(const short8*)(&Kl[(colt + m16) * KP + 32 + quad * 8]);
                float4v s = __builtin_amdgcn_mfma_f32_16x16x32_bf16(
                                A0, QA0, (float4v){0.f,0.f,0.f,0.f}, 0, 0, 0);
                s = __builtin_amdgcn_mfma_f32_16x16x32_bf16(A1, QA1, s, 0, 0, 0);
                float p0 = exp2f(s[0] + LOG2E);
                float p1 = exp2f(s[1] + LOG2E);
                float p2 = exp2f(s[2] + LOG2E);
                float p3 = exp2f(s[3] + LOG2E);
                lA += (p0 + p1) + (p2 + p3);
                uint32_t u0, u1;
                asm("v_cvt_pk_bf16_f32 %0, %1, %2" : "=v"(u0) : "v"(p0), "v"(p1));
                asm("v_cvt_pk_bf16_f32 %0, %1, %2" : "=v"(u1) : "v"(p2), "v"(p3));
                uint2v uu; uu[0] = u0; uu[1] = u1;
                *(uint2v*)(&Pw[m16 * PPs + ct * 16 + quad * 4]) = uu;
            }
            asm volatile("s_waitcnt lgkmcnt(0)" ::: "memory");
            short8 PfA = *(const short8*)(&Pw[m16 * PPs + quad * 8]);
            // ---- pass B: QK + exp for row set B (A-frags re-read) ----
            #pragma unroll
            for (int ct = 0; ct < 2; ++ct){
                int colt = kg * 32 + ct * 16;
                short8 A0 = *(const short8*)(&Kl[(colt + m16) * KP + quad * 8]);
                short8 A1 = *(const short8*)(&Kl[(colt + m16) * KP + 32 + quad * 8]);
                float4v s = __builtin_amdgcn_mfma_f32_16x16x32_bf16(
                                A0, QB0, (float4v){0.f,0.f,0.f,0.f}, 0, 0, 0);
                s = __builtin_amdgcn_mfma_f32_16x16x32_bf16(A1, QB1, s, 0, 0, 0);
                float p0 = exp2f(s[0] + LOG2E);
                float p1 = exp2f(s[1] + LOG2E);
                float p2 = exp2f(s[2] + LOG2E);
                float p3 = exp2f(s[3] + LOG2E);
                lB += (p0 + p1) + (p2 + p3);
                uint32_t u0, u1;
                asm("v_cvt_pk_bf16_f32 %0, %1, %2" : "=v"(u0) : "v"(p0), "v"(p1));
                asm("v_cvt_pk_bf16_f32 %0, %1, %2" : "=v"(u1) : "v"(p2), "v"(p3));
                uint2v uu; uu[0] = u0; uu[1] = u1;
                *(uint2v*)(&Pw[m16 * PPs + ct * 16 + quad * 4]) = uu;
            }
            asm volatile("s_waitcnt lgkmcnt(0)" ::: "memory");
            short8 PfB = *(const short8*)(&Pw[m16 * PPs + quad * 8]);
            // ---- PV: each Va fragment feeds BOTH row sets ----
            #pragma unroll
            for (int dt = 0; dt < 4; ++dt){
                short8 Va = *(const short8*)(&Vl[(dt * 16 + m16) * VP + kg * 32 + quad * 8]);
                OcA[dt] = __builtin_amdgcn_mfma_f32_16x16x32_bf16(Va, PfA, OcA[dt], 0, 0, 0);
                OcB[dt] = __builtin_amdgcn_mfma_f32_16x16x32_bf16(Va, PfB, OcB[dt], 0, 0, 0);
            }
        }
        __syncthreads();
    }
    lA += __shfl_xor(lA, 16, 64);
    lA += __shfl_xor(lA, 32, 64);
    lB += __shfl_xor(lB, 16, 64);
    lB += __shfl_xor(lB, 32, 64);
    size_t slab = (size_t)(cs * 2 + sg);
    if (quad == 0){
        ws[OF_LP + slab * N + rowA + m16] = lA;
        ws[OF_LP + slab * N + rowB + m16] = lB;
    }
    float* OpA = ws + OF_OP + (slab * N + rowA + m16) * 64;
    float* OpB = ws + OF_OP + (slab * N + rowB + m16) * 64;
    #pragma unroll
    for (int dt = 0; dt < 4; ++dt)
        #pragma unroll
        for (int r = 0; r < 4; ++r){
            OpA[dt * 16 + quad * 4 + r] = OcA[dt][r];
            OpB[dt * 16 + quad * 4 + r] = OcB[dt][r];
        }
}

// ---- K2: attn || fill (complementary pairing) ----
__global__ void __launch_bounds__(256, 6)
attn_fill_kernel(const int* __restrict__ eip, const int* __restrict__ ein,
                 uint32_t* __restrict__ iws,
                 const float* __restrict__ ws_ro, float* __restrict__ ws){
    __shared__ __align__(16) short Kl[64 * 72];
    __shared__ __align__(16) short Vl[64 * 72];
    __shared__ __align__(16) short Pls[4][16 * 40];
    int b = blockIdx.x, t = threadIdx.x;
    if (b < 768){                            // ---- bucket fill ----
        int e = b * 256 + t;                 // always < Eg (768*256 == Eg)
        uint32_t* Cu  = iws + OI_CUR;
        uint32_t* Pay = iws + OI_PAY;
        int rp = clampi(eip[e]), cp = clampi(eip[Eg + e]);
        int rn = clampi(ein[e]), cn = clampi(ein[Eg + e]);
        uint32_t s;
        s = atomicAdd(&Cu[0 * N + rp], 1u); if (s < PAYC) Pay[((size_t)0 * N + rp) * PAYC + s] = (uint32_t)e | ((uint32_t)cp << 18);
        s = atomicAdd(&Cu[1 * N + cp], 1u); if (s < PAYC) Pay[((size_t)1 * N + cp) * PAYC + s] = (uint32_t)e | ((uint32_t)rp << 18);
        s = atomicAdd(&Cu[2 * N + rn], 1u); if (s < PAYC) Pay[((size_t)2 * N + rn) * PAYC + s] = (uint32_t)e | ((uint32_t)cn << 18);
        s = atomicAdd(&Cu[3 * N + cn], 1u); if (s < PAYC) Pay[((size_t)3 * N + cn) * PAYC + s] = (uint32_t)e | ((uint32_t)rn << 18);
        return;
    }
    attn_role(b - 768, Kl, Vl, Pls, ws_ro, ws);
}

// ---- merged mean+corr (R17): adjacency walked once; three gather streams.
__device__ __forceinline__ void meancorr_role(int b,
        const void* __restrict__ x1, const void* __restrict__ x2, uint32_t fA,
        const uint32_t* __restrict__ iws, const float* __restrict__ ws_ro,
        float* __restrict__ ws, float* __restrict__ O, float* __restrict__ Lg){
    int wid = threadIdx.x >> 6, lane = threadIdx.x & 63;
    int gw = b * 4 + wid;
    int sg = gw >= N;
    int i = gw - sg * N;
    int grp = lane >> 4, gl = lane & 15;
    const void* x = sg ? x2 : x1;
    const bf* Qb = (const bf*)(ws_ro + OF_QKVB) + (size_t)(sg * 3) * NF;
    const bf* Kb = Qb + NF;
    const bf* Vb = Kb + NF;
    const int csr = sg ? 2 : 0;
    uint32_t cnt = iws[OI_CUR + (size_t)csr * N + i];
    if (cnt > (uint32_t)PAYC) cnt = PAYC;
    const uint32_t* Pay = iws + OI_PAY + ((size_t)csr * N + i) * PAYC;
    short4v q4 = *(const short4v*)((const short*)Qb + (size_t)i * 64 + gl * 4);
    float q0 = s2f(q4[0]), q1 = s2f(q4[1]), q2 = s2f(q4[2]), q3 = s2f(q4[3]);
    float4v acc = (float4v){0.f, 0.f, 0.f, 0.f};
    float4v xm  = (float4v){0.f, 0.f, 0.f, 0.f};
    float accL = 0.f;
    constexpr float C = 0.63212055882f;      // 1 - 1/e
    for (uint32_t p = (uint32_t)grp; p <= cnt; p += 4){
        int c = (p < cnt) ? (int)(Pay[p] >> 18) : i;   // p==cnt -> diagonal/self
        if (fA){
            float4v xv = *(const float4v*)((const float*)x + (size_t)c * 64 + gl * 4);
            xm[0] += sane(xv[0]); xm[1] += sane(xv[1]);
            xm[2] += sane(xv[2]); xm[3] += sane(xv[3]);
        } else {
            short4v xv = *(const short4v*)((const short*)x + (size_t)c * 64 + gl * 4);
            xm[0] += sane(s2f(xv[0])); xm[1] += sane(s2f(xv[1]));
            xm[2] += sane(s2f(xv[2])); xm[3] += sane(s2f(xv[3]));
        }
        short4v k4 = *(const short4v*)((const short*)Kb + (size_t)c * 64 + gl * 4);
        float s = q0 * s2f(k4[0]) + q1 * s2f(k4[1]) + q2 * s2f(k4[2]) + q3 * s2f(k4[3]);
        s += __shfl_xor(s, 1, 64); s += __shfl_xor(s, 2, 64);
        s += __shfl_xor(s, 4, 64); s += __shfl_xor(s, 8, 64);
        float f = C * exp2f(s + LOG2E);
        short4v v4 = *(const short4v*)((const short*)Vb + (size_t)c * 64 + gl * 4);
        acc[0] += f * s2f(v4[0]); acc[1] += f * s2f(v4[1]);
        acc[2] += f * s2f(v4[2]); acc[3] += f * s2f(v4[3]);
        accL += f;
    }
    // OP/LP slab partial for this group's two slabs (R16)
    size_t slabA = (size_t)((2 * grp) * 2 + sg), slabB = (size_t)((2 * grp + 1) * 2 + sg);
    float4v opA = *(const float4v*)(ws_ro + OF_OP + (slabA * N + i) * 64 + gl * 4);
    float4v opB = *(const float4v*)(ws_ro + OF_OP + (slabB * N + i) * 64 + gl * 4);
    float4v op;
    #pragma unroll
    for (int j = 0; j < 4; ++j) op[j] = opA[j] + opB[j];
    float lp = (gl == 0) ? (ws_ro[OF_LP + slabA * N + i] + ws_ro[OF_LP + slabB * N + i]) : 0.f;
    #pragma unroll
    for (int j = 0; j < 4; ++j){
        acc[j] += __shfl_xor(acc[j], 16, 64);
        acc[j] += __shfl_xor(acc[j], 32, 64);
        op[j]  += __shfl_xor(op[j], 16, 64);
        op[j]  += __shfl_xor(op[j], 32, 64);
        xm[j]  += __shfl_xor(xm[j], 16, 64);
        xm[j]  += __shfl_xor(xm[j], 32, 64);
    }
    accL += __shfl_xor(accL, 16, 64);
    accL += __shfl_xor(accL, 32, 64);
    lp   += __shfl_xor(lp, 16, 64);
    lp   += __shfl_xor(lp, 32, 64);
    if (grp == 0){
        float4v o, mn;
        #pragma unroll
        for (int j = 0; j < 4; ++j){
            o[j]  = op[j] - acc[j];
            mn[j] = sane(xm[j] / (float)(cnt + 1));
        }
        *(float4v*)(&O[((size_t)sg * N + i) * 64 + gl * 4]) = o;
        *(float4v*)(&ws[OF_MEAN + ((size_t)sg * N + i) * 64 + gl * 4]) = mn;
    }
    if (lane == 0) Lg[(size_t)sg * N + i] = lp - accL;
}

__device__ __forceinline__ void pool_role(int b, const void* __restrict__ efp,
                                          const void* __restrict__ efn,
                                          const uint32_t* __restrict__ iws,
                                          uint32_t fB, float* __restrict__ ws){
    int wid = threadIdx.x >> 6, lane = threadIdx.x & 63;
    int gw = b * 4 + wid;
    int g = gw / N, i = gw - g * N;
    const void* ef = (g < 2) ? efp : efn;
    uint32_t cnt = iws[OI_CUR + (size_t)g * N + i];
    if (cnt > (uint32_t)PAYC) cnt = PAYC;
    const uint32_t* Pay = iws + OI_PAY + ((size_t)g * N + i) * PAYC;
    int f = lane & 31, h = lane >> 5;
    float m = 0.f;
    uint32_t p = h;
    if (fB){
        const float* E = (const float*)ef;
        for (; p + 2 < cnt; p += 4){
            uint32_t e0 = Pay[p] & 0x3FFFFu, e1 = Pay[p + 2] & 0x3FFFFu;
            m = fmaxf(m, fmaxf(E[(size_t)e0 * 32 + f], E[(size_t)e1 * 32 + f]));
        }
        for (; p < cnt; p += 2)
            m = fmaxf(m, E[(size_t)(Pay[p] & 0x3FFFFu) * 32 + f]);
    } else {
        const bf* E = (const bf*)ef;
        for (; p + 2 < cnt; p += 4){
            uint32_t e0 = Pay[p] & 0x3FFFFu, e1 = Pay[p + 2] & 0x3FFFFu;
            m = fmaxf(m, fmaxf(b2f(E[(size_t)e0 * 32 + f]), b2f(E[(size_t)e1 * 32 + f])));
        }
        for (; p < cnt; p += 2)
            m = fmaxf(m, b2f(E[(size_t)(Pay[p] & 0x3FFFFu) * 32 + f]));
    }
    m = fmaxf(m, __shfl_xor(m, 32, 64));
    m = sane(m);
    float ss = m * m;
    ss += __shfl_xor(ss, 16, 64); ss += __shfl_xor(ss, 8, 64);
    ss += __shfl_xor(ss, 4, 64);  ss += __shfl_xor(ss, 2, 64);
    ss += __shfl_xor(ss, 1, 64);
    float r = m / fmaxf(sqrtf(ss), 1e-12f);
    if (lane < 32) ws[OF_POOL + ((size_t)g * N + i) * 32 + f] = sane(r);
}

__global__ void mega_kernel(const void* __restrict__ x1, const void* __restrict__ x2,
                            const void* __restrict__ efp, const void* __restrict__ efn,
                            const uint32_t* __restrict__ iws,
                            const float* __restrict__ ws_ro, float* __restrict__ ws){
    int b = blockIdx.x;
    const uint32_t* flags = iws + OI_FLAG;
    if (b < 3072) meancorr_role(b, x1, x2, flags[0], iws, ws_ro, ws,
                                ws + OF_O, ws + OF_L);
    else          pool_role(b - 3072, efp, efn, iws, flags[1], ws);
}

// ---- K4: O/L (pre-reduced) -> @Wo+bo -> +mean -> concat -> @weight+bias -> L2
__global__ void final_kernel(const void* __restrict__ x1, const void* __restrict__ x2,
                             const uint32_t* __restrict__ iws,
                             const float* __restrict__ ws, void* __restrict__ outv){
    uint32_t fA = iws[OI_FLAG + 0];
    int wid = threadIdx.x >> 6, c = threadIdx.x & 63;
    int i = blockIdx.x * 4 + wid;
    __shared__ float feat[4][384];
    __shared__ float onrm[4][64];
    for (int s = 0; s < 2; ++s){
        float osum = ws[OF_O + ((size_t)s * N + i) * 64 + c];
        float lsum = ws[OF_L + (size_t)s * N + i];
        onrm[wid][c] = sane(osum / fmaxf(lsum, 1e-20f));
        __syncthreads();
        const float* Wo = ws + OF_WO + (size_t)s * 4096;
        float attn = ws[OF_BO + s * 64 + c];
        #pragma unroll 8
        for (int d = 0; d < 64; ++d) attn += onrm[wid][d] * Wo[d * 64 + c];
        feat[wid][s * 64 + c] = sane(ws[OF_MEAN + (size_t)s * NF + (size_t)i * 64 + c] + attn);
        __syncthreads();
    }
    feat[wid][128 + c] = sane(ldf(x1, (size_t)i * 64 + c, fA));
    feat[wid][192 + c] = sane(ldf(x2, (size_t)i * 64 + c, fA));
    {
        int g0 = c >> 5, f = c & 31;
        feat[wid][256 + c] = ws[OF_POOL + ((size_t)g0 * N + i) * 32 + f];
        feat[wid][320 + c] = ws[OF_POOL + ((size_t)(2 + g0) * N + i) * 32 + f];
    }
    __syncthreads();
    float acc = ws[OF_BF + c];
    #pragma unroll 8
    for (int k = 0; k < 384; ++k) acc += feat[wid][k] * ws[OF_WF + (size_t)k * 64 + c];
    acc = sane(acc);
    float ss = acc * acc;
    ss += __shfl_xor(ss, 32, 64); ss += __shfl_xor(ss, 16, 64); ss += __shfl_xor(ss, 8, 64);
    ss += __shfl_xor(ss, 4, 64);  ss += __shfl_xor(ss, 2, 64);  ss += __shfl_xor(ss, 1, 64);
    float r = acc / fmaxf(sqrtf(ss), 1e-12f);
    if (fA) ((float*)outv)[(size_t)i * 64 + c] = r;
    else    ((bf*)outv)[(size_t)i * 64 + c] = __float2bfloat16(r);
}

extern "C" void kernel_launch(void* const* d_in, const int* in_sizes, int n_in,
                              void* d_out, int out_size, void* d_ws, size_t ws_size,
                              hipStream_t stream){
    const int* eip = (const int*)d_in[2];
    const int* ein = (const int*)d_in[3];

    float* ws = (float*)d_ws;
    uint32_t* iws = (uint32_t*)(ws + F_TOTAL);

    // 1) QKV GEMV || Wo/final staging || flags || counter-zero (no memsets)
    qkv_stage_kernel<<<dim3(9216 + 129 + 1 + 96), 256, 0, stream>>>(
        d_in[0], d_in[1],
        d_in[8],  d_in[10], d_in[12], d_in[16], d_in[18], d_in[20],
        d_in[9],  d_in[11], d_in[13], d_in[17], d_in[19], d_in[21],
        d_in[14], d_in[15], d_in[22], d_in[23],
        d_in[6],  d_in[7],  d_in[4],
        iws, ws);
    // 2) bucket fill (768, atomics, first) || dense MFMA attention (768 blocks,
    //    128 rows each — staging amortized over 2x MFMA work)
    attn_fill_kernel<<<dim3(768 + 768), 256, 0, stream>>>(eip, ein, iws, ws, ws);
    // 3) merged mean+corr (3072, walks adjacency once) || pool (6144)
    mega_kernel<<<dim3(3072 + 6144), 256, 0, stream>>>(d_in[0], d_in[1], d_in[4], d_in[5],
                                                       iws, ws, ws);
    // 4) epilogue (reads pre-reduced O/L)
    final_kernel<<<dim3(N / 4), 256, 0, stream>>>(d_in[0], d_in[1], iws, ws, d_out);
}

// Round 19
// 311.693 us; speedup vs baseline: 1.2991x; 1.2991x over previous
//
#include <hip/hip_runtime.h>
#include <hip/hip_bf16.h>
#include <stdint.h>

typedef __hip_bfloat16 bf;
typedef __attribute__((ext_vector_type(8))) short short8;
typedef __attribute__((ext_vector_type(4))) short short4v;
typedef __attribute__((ext_vector_type(4))) float float4v;
typedef __attribute__((ext_vector_type(2))) unsigned int uint2v;
__device__ __forceinline__ float b2f(bf x){ return __bfloat162float(x); }
__device__ __forceinline__ float s2f(short s){ union{ short s_; bf b_; } u; u.s_ = s; return b2f(u.b_); }
__device__ __forceinline__ float sane(float x){ return fminf(fmaxf(x, -1e6f), 1e6f); }

// Problem constants
constexpr int N   = 6144;          // NOT a power of two (3*2^11)!
constexpr int D   = 64;
constexpr int FE  = 32;
constexpr int Eg  = 196608;        // < 2^18 -> edge id packs in 18 bits; 768*256 == Eg
constexpr size_t NF = (size_t)N * D;
constexpr float LOG2E = 1.44269504088896340736f;
// Degrees ~ Poisson(32). P(deg > 96) ~ 1e-18/node -> fixed-capacity buckets.
constexpr int PAYC = 96;

__device__ __forceinline__ int clampi(int v){ return v < 0 ? 0 : (v >= N ? N - 1 : v); }
__device__ __forceinline__ float ldf(const void* p, size_t i, uint32_t isf32){
    return isf32 ? ((const float*)p)[i] : b2f(((const bf*)p)[i]);
}

// ---- float workspace layout (floats) ----  ~39 MB
constexpr size_t OF_OP   = 0;                           // [8][2][N][D]
constexpr size_t OF_LP   = OF_OP + 16*NF;               // [8][2][N]
constexpr size_t OF_MEAN = OF_LP + 16*(size_t)N;        // [2][N][D]
constexpr size_t OF_POOL = OF_MEAN + 2*NF;              // [4][N][FE]
constexpr size_t OF_QKVB = OF_POOL + (size_t)4*N*FE;    // bf16 [2][3][N][D] (Q pre-scaled)
constexpr size_t OF_WO   = OF_QKVB + 3*NF;              // [2][64][64] Wo_p, Wo_n
constexpr size_t OF_BO   = OF_WO + 8192;                // [2][64]
constexpr size_t OF_WF   = OF_BO + 128;                 // [384][64] final weight
constexpr size_t OF_BF   = OF_WF + 24576;               // [64]
constexpr size_t OF_O    = OF_BF + 64;                  // [2][N][D] FINAL attn numerator (corr-reduced)
constexpr size_t OF_L    = OF_O + 2*NF;                 // [2][N]    FINAL attn denominator
constexpr size_t F_TOTAL = OF_L + 2*(size_t)N;
// ---- u32 workspace (words, after float region) ----  ~9.5 MB
constexpr size_t OI_CUR  = 0;                           // [4][N] bucket counters
constexpr size_t OI_PAY  = OI_CUR + 4*(size_t)N;        // [4][N][PAYC] payload: e | (other<<18)
constexpr size_t OI_FLAG = OI_PAY + 4*(size_t)N*PAYC;   // [4] dtype flags

// per-wave dtype sniff, no sync needed: all lanes end with identical flag.
__device__ __forceinline__ uint32_t wave_sniff(const void* p){
    const bf* q = (const bf*)p;
    int lane = threadIdx.x & 63;
    float m = 0.f;
    #pragma unroll
    for (int k = 0; k < 4; ++k){
        float v = fabsf(b2f(q[lane + 64*k]));
        if (!(v <= 1e9f)) v = 1e9f;
        m = fmaxf(m, v);
    }
    m = fmaxf(m, __shfl_xor(m, 32, 64));
    m = fmaxf(m, __shfl_xor(m, 16, 64));
    m = fmaxf(m, __shfl_xor(m, 8, 64));
    m = fmaxf(m, __shfl_xor(m, 4, 64));
    m = fmaxf(m, __shfl_xor(m, 2, 64));
    m = fmaxf(m, __shfl_xor(m, 1, 64));
    return (m > 100.f) ? 1u : 0u;
}

// ---- K1: QKV GEMV from RAW inputs || Wo/final-W staging || flags ||
// counter-zero (replaces the memset launch; fill runs in K2 -> ordering safe).
__global__ void qkv_stage_kernel(const void* x1, const void* x2,
                                 const void* W0, const void* W1, const void* W2,
                                 const void* W3, const void* W4, const void* W5,
                                 const void* B0, const void* B1, const void* B2,
                                 const void* B3, const void* B4, const void* B5,
                                 const void* Wop, const void* bop,
                                 const void* Won, const void* bon,
                                 const void* wgt, const void* bia,
                                 const void* efp,
                                 uint32_t* __restrict__ iws, float* __restrict__ ws){
    int b = blockIdx.x, t = threadIdx.x;
    if (b < 9216){                           // ---- QKV GEMV from raw inputs ----
        int m = b / 1536;
        int wid = t >> 6, lane = t & 63;
        int i = (b % 1536) * 4 + wid;
        const void* xr = (m < 3) ? x1 : x2;
        const void* Wr = (m==0)?W0:(m==1)?W1:(m==2)?W2:(m==3)?W3:(m==4)?W4:W5;
        const void* Br = (m==0)?B0:(m==1)?B1:(m==2)?B2:(m==3)?B3:(m==4)?B4:B5;
        uint32_t fA = wave_sniff(xr);
        uint32_t fD = wave_sniff(W0);
        float xreg = sane(ldf(xr, (size_t)i * 64 + lane, fA));
        float acc;
        if (fD){                             // wave-uniform: typed f32 path
            const float* W = (const float*)Wr;
            acc = sane(((const float*)Br)[lane]);
            #pragma unroll 16
            for (int d = 0; d < 64; ++d)
                acc += __shfl(xreg, d, 64) * sane(W[d * 64 + lane]);
        } else {                             // typed bf16 path
            const bf* W = (const bf*)Wr;
            acc = sane(b2f(((const bf*)Br)[lane]));
            #pragma unroll 16
            for (int d = 0; d < 64; ++d)
                acc += __shfl(xreg, d, 64) * sane(b2f(W[d * 64 + lane]));
        }
        acc = sane(acc);
        if (m == 0 || m == 3) acc *= (0.125f * LOG2E);   // fold softmax scale AND log2e into Q
        bf* qkvb = (bf*)(ws + OF_QKVB);
        qkvb[(size_t)m * NF + (size_t)i * 64 + lane] = __float2bfloat16(acc);
        return;
    }
    b -= 9216;
    if (b < 129){                            // ---- Wo/bo + final W/b staging ----
        size_t idx = (size_t)b * 256 + t;
        uint32_t fD = wave_sniff(Wop);       // sniff BEFORE any early return (wave uniform)
        uint32_t fC = wave_sniff(wgt);
        if (idx >= 32960) return;
        if (idx < 8192){
            int k = (int)(idx >> 12), sub = (int)(idx & 4095);
            ws[OF_WO + idx] = sane(ldf(k ? Won : Wop, sub, fD));
        } else if (idx < 8320){
            int k = (int)((idx - 8192) >> 6), sub = (int)(idx & 63);
            ws[OF_BO + (idx - 8192)] = sane(ldf(k ? bon : bop, sub, fD));
        } else if (idx < 32896){
            ws[OF_WF + (idx - 8320)] = sane(ldf(wgt, idx - 8320, fC));
        } else {
            ws[OF_BF + (idx - 32896)] = sane(ldf(bia, idx - 32896, fC));
        }
        return;
    }
    if (b == 129){                           // ---- flags block (x fA, pool fB, final) ----
        __shared__ float red[256];
        uint32_t* flags = iws + OI_FLAG;
        const void* ps[4] = {x1, efp, wgt, W0};
        for (int k = 0; k < 4; ++k){
            const bf* p = (const bf*)ps[k];
            float m = 0.f;
            for (int i = t; i < 1024; i += 256){
                float v = fabsf(b2f(p[i]));
                if (!(v <= 1e9f)) v = 1e9f;
                m = fmaxf(m, v);
            }
            red[t] = m; __syncthreads();
            for (int off = 128; off; off >>= 1){
                if (t < off) red[t] = fmaxf(red[t], red[t + off]);
                __syncthreads();
            }
            if (t == 0) flags[k] = (red[0] > 100.f) ? 1u : 0u;
            __syncthreads();
        }
        return;
    }
    {                                        // ---- zero bucket counters (96 blocks) ----
        int z = (b - 130) * 256 + t;         // 96*256 == 4*N exactly
        iws[OI_CUR + z] = 0u;
    }
}

// ---- attn role: 1536 blocks = 8 strips x 96 row-tiles x 2 signs (12 tiles
// each). Plain-store partials into OP/LP slab cs*2+sg. (R17-exact: R18's
// 128-row variant spilled to scratch — WRITE_SIZE 66->371MB — and cost 89us.)
__device__ __forceinline__ void attn_role(int b, short* __restrict__ Kl,
                                          short* __restrict__ Vl,
                                          short (* __restrict__ Pls)[16 * 40],
                                          const float* __restrict__ ws_ro,
                                          float* __restrict__ ws){
    constexpr int KP = 72;
    constexpr int VP = 72;
    constexpr int PPs = 40;
    const bf* qkvb = (const bf*)(ws_ro + OF_QKVB);

    int tid = threadIdx.x, lane = tid & 63, wv = tid >> 6;
    int m16 = lane & 15, quad = lane >> 4;
    int rt = b % 96, cs = (b / 96) & 7, sg = b / 768;
    const bf* Qb = qkvb + (size_t)(sg * 3) * NF;
    const bf* Kb = Qb + NF;
    const bf* Vb = Kb + NF;

    int rowbase = rt * 64 + wv * 16;
    short8 Qf0 = *(const short8*)(Qb + (size_t)(rowbase + m16) * 64 + quad * 8);
    short8 Qf1 = *(const short8*)(Qb + (size_t)(rowbase + m16) * 64 + 32 + quad * 8);

    float4v Oc[4];
    #pragma unroll
    for (int t = 0; t < 4; ++t) Oc[t] = (float4v){0.f, 0.f, 0.f, 0.f};
    float l = 0.f;

    int scol = tid & 63, sgrp = tid >> 6;
    int c0 = cs * (N / 8), c1 = c0 + N / 8;  // 12 tiles of 64
    for (int cb = c0; cb < c1; cb += 64){
        {
            const short* ksrc = (const short*)(Kb + (size_t)(cb + scol) * 64 + sgrp * 16);
            *(short8*)(&Kl[scol * KP + sgrp * 16])     = *(const short8*)(ksrc);
            *(short8*)(&Kl[scol * KP + sgrp * 16 + 8]) = *(const short8*)(ksrc + 8);
            const short* vsrc = (const short*)(Vb + (size_t)(cb + scol) * 64 + sgrp * 16);
            short8 v0 = *(const short8*)(vsrc);
            short8 v1 = *(const short8*)(vsrc + 8);
            #pragma unroll
            for (int j = 0; j < 8; ++j) Vl[(sgrp * 16 + j) * VP + scol] = v0[j];
            #pragma unroll
            for (int j = 0; j < 8; ++j) Vl[(sgrp * 16 + 8 + j) * VP + scol] = v1[j];
        }
        __syncthreads();

        short* Pw = Pls[wv];
        #pragma unroll
        for (int kg = 0; kg < 2; ++kg){
            #pragma unroll
            for (int ct = 0; ct < 2; ++ct){
                int colt = kg * 32 + ct * 16;
                short8 A0 = *(const short8*)(&Kl[(colt + m16) * KP + quad * 8]);
                short8 A1 = *(const short8*)(&Kl[(colt + m16) * KP + 32 + quad * 8]);
                float4v s = __builtin_amdgcn_mfma_f32_16x16x32_bf16(
                                A0, Qf0, (float4v){0.f,0.f,0.f,0.f}, 0, 0, 0);
                s = __builtin_amdgcn_mfma_f32_16x16x32_bf16(A1, Qf1, s, 0, 0, 0);
                float p0 = exp2f(s[0] + LOG2E);
                float p1 = exp2f(s[1] + LOG2E);
                float p2 = exp2f(s[2] + LOG2E);
                float p3 = exp2f(s[3] + LOG2E);
                l += (p0 + p1) + (p2 + p3);
                uint32_t u0, u1;
                asm("v_cvt_pk_bf16_f32 %0, %1, %2" : "=v"(u0) : "v"(p0), "v"(p1));
                asm("v_cvt_pk_bf16_f32 %0, %1, %2" : "=v"(u1) : "v"(p2), "v"(p3));
                uint2v uu; uu[0] = u0; uu[1] = u1;
                *(uint2v*)(&Pw[m16 * PPs + ct * 16 + quad * 4]) = uu;
            }
            asm volatile("s_waitcnt lgkmcnt(0)" ::: "memory");
            short8 Pf = *(const short8*)(&Pw[m16 * PPs + quad * 8]);
            #pragma unroll
            for (int dt = 0; dt < 4; ++dt){
                short8 Va = *(const short8*)(&Vl[(dt * 16 + m16) * VP + kg * 32 + quad * 8]);
                Oc[dt] = __builtin_amdgcn_mfma_f32_16x16x32_bf16(Va, Pf, Oc[dt], 0, 0, 0);
            }
        }
        __syncthreads();
    }
    l += __shfl_xor(l, 16, 64);
    l += __shfl_xor(l, 32, 64);
    size_t slab = (size_t)(cs * 2 + sg);
    if (quad == 0) ws[OF_LP + slab * N + rowbase + m16] = l;
    float* Op = ws + OF_OP + (slab * N + rowbase + m16) * 64;
    #pragma unroll
    for (int dt = 0; dt < 4; ++dt)
        #pragma unroll
        for (int r = 0; r < 4; ++r)
            Op[dt * 16 + quad * 4 + r] = Oc[dt][r];
}

// ---- K2: attn || fill (R12-proven complementary pairing, ~88us) ----
__global__ void __launch_bounds__(256, 6)
attn_fill_kernel(const int* __restrict__ eip, const int* __restrict__ ein,
                 uint32_t* __restrict__ iws,
                 const float* __restrict__ ws_ro, float* __restrict__ ws){
    __shared__ __align__(16) short Kl[64 * 72];
    __shared__ __align__(16) short Vl[64 * 72];
    __shared__ __align__(16) short Pls[4][16 * 40];
    int b = blockIdx.x, t = threadIdx.x;
    if (b < 768){                            // ---- bucket fill ----
        int e = b * 256 + t;                 // always < Eg (768*256 == Eg)
        uint32_t* Cu  = iws + OI_CUR;
        uint32_t* Pay = iws + OI_PAY;
        int rp = clampi(eip[e]), cp = clampi(eip[Eg + e]);
        int rn = clampi(ein[e]), cn = clampi(ein[Eg + e]);
        uint32_t s;
        s = atomicAdd(&Cu[0 * N + rp], 1u); if (s < PAYC) Pay[((size_t)0 * N + rp) * PAYC + s] = (uint32_t)e | ((uint32_t)cp << 18);
        s = atomicAdd(&Cu[1 * N + cp], 1u); if (s < PAYC) Pay[((size_t)1 * N + cp) * PAYC + s] = (uint32_t)e | ((uint32_t)rp << 18);
        s = atomicAdd(&Cu[2 * N + rn], 1u); if (s < PAYC) Pay[((size_t)2 * N + rn) * PAYC + s] = (uint32_t)e | ((uint32_t)cn << 18);
        s = atomicAdd(&Cu[3 * N + cn], 1u); if (s < PAYC) Pay[((size_t)3 * N + cn) * PAYC + s] = (uint32_t)e | ((uint32_t)rn << 18);
        return;
    }
    attn_role(b - 768, Kl, Vl, Pls, ws_ro, ws);
}

// ---- merged mean+corr (R17): same adjacency walked ONCE; per edge, three
// independent gather streams (x, K, V) overlap L2 latency. Diagonal iteration
// doubles as mean's self-loop (exactly-once). The shared xor16/32 butterfly
// reduces xm alongside acc/op; grp0 writes MEAN and final O; lane0 writes L.
__device__ __forceinline__ void meancorr_role(int b,
        const void* __restrict__ x1, const void* __restrict__ x2, uint32_t fA,
        const uint32_t* __restrict__ iws, const float* __restrict__ ws_ro,
        float* __restrict__ ws, float* __restrict__ O, float* __restrict__ Lg){
    int wid = threadIdx.x >> 6, lane = threadIdx.x & 63;
    int gw = b * 4 + wid;
    int sg = gw >= N;
    int i = gw - sg * N;
    int grp = lane >> 4, gl = lane & 15;
    const void* x = sg ? x2 : x1;
    const bf* Qb = (const bf*)(ws_ro + OF_QKVB) + (size_t)(sg * 3) * NF;
    const bf* Kb = Qb + NF;
    const bf* Vb = Kb + NF;
    const int csr = sg ? 2 : 0;
    uint32_t cnt = iws[OI_CUR + (size_t)csr * N + i];
    if (cnt > (uint32_t)PAYC) cnt = PAYC;
    const uint32_t* Pay = iws + OI_PAY + ((size_t)csr * N + i) * PAYC;
    short4v q4 = *(const short4v*)((const short*)Qb + (size_t)i * 64 + gl * 4);
    float q0 = s2f(q4[0]), q1 = s2f(q4[1]), q2 = s2f(q4[2]), q3 = s2f(q4[3]);
    float4v acc = (float4v){0.f, 0.f, 0.f, 0.f};
    float4v xm  = (float4v){0.f, 0.f, 0.f, 0.f};
    float accL = 0.f;
    constexpr float C = 0.63212055882f;      // 1 - 1/e
    for (uint32_t p = (uint32_t)grp; p <= cnt; p += 4){
        int c = (p < cnt) ? (int)(Pay[p] >> 18) : i;   // p==cnt -> diagonal/self
        if (fA){
            float4v xv = *(const float4v*)((const float*)x + (size_t)c * 64 + gl * 4);
            xm[0] += sane(xv[0]); xm[1] += sane(xv[1]);
            xm[2] += sane(xv[2]); xm[3] += sane(xv[3]);
        } else {
            short4v xv = *(const short4v*)((const short*)x + (size_t)c * 64 + gl * 4);
            xm[0] += sane(s2f(xv[0])); xm[1] += sane(s2f(xv[1]));
            xm[2] += sane(s2f(xv[2])); xm[3] += sane(s2f(xv[3]));
        }
        short4v k4 = *(const short4v*)((const short*)Kb + (size_t)c * 64 + gl * 4);
        float s = q0 * s2f(k4[0]) + q1 * s2f(k4[1]) + q2 * s2f(k4[2]) + q3 * s2f(k4[3]);
        s += __shfl_xor(s, 1, 64); s += __shfl_xor(s, 2, 64);
        s += __shfl_xor(s, 4, 64); s += __shfl_xor(s, 8, 64);
        float f = C * exp2f(s + LOG2E);
        short4v v4 = *(const short4v*)((const short*)Vb + (size_t)c * 64 + gl * 4);
        acc[0] += f * s2f(v4[0]); acc[1] += f * s2f(v4[1]);
        acc[2] += f * s2f(v4[2]); acc[3] += f * s2f(v4[3]);
        accL += f;
    }
    // OP/LP slab partial for this group's two slabs (R16)
    size_t slabA = (size_t)((2 * grp) * 2 + sg), slabB = (size_t)((2 * grp + 1) * 2 + sg);
    float4v opA = *(const float4v*)(ws_ro + OF_OP + (slabA * N + i) * 64 + gl * 4);
    float4v opB = *(const float4v*)(ws_ro + OF_OP + (slabB * N + i) * 64 + gl * 4);
    float4v op;
    #pragma unroll
    for (int j = 0; j < 4; ++j) op[j] = opA[j] + opB[j];
    float lp = (gl == 0) ? (ws_ro[OF_LP + slabA * N + i] + ws_ro[OF_LP + slabB * N + i]) : 0.f;
    #pragma unroll
    for (int j = 0; j < 4; ++j){
        acc[j] += __shfl_xor(acc[j], 16, 64);
        acc[j] += __shfl_xor(acc[j], 32, 64);
        op[j]  += __shfl_xor(op[j], 16, 64);
        op[j]  += __shfl_xor(op[j], 32, 64);
        xm[j]  += __shfl_xor(xm[j], 16, 64);
        xm[j]  += __shfl_xor(xm[j], 32, 64);
    }
    accL += __shfl_xor(accL, 16, 64);
    accL += __shfl_xor(accL, 32, 64);
    lp   += __shfl_xor(lp, 16, 64);
    lp   += __shfl_xor(lp, 32, 64);
    if (grp == 0){
        float4v o, mn;
        #pragma unroll
        for (int j = 0; j < 4; ++j){
            o[j]  = op[j] - acc[j];
            mn[j] = sane(xm[j] / (float)(cnt + 1));
        }
        *(float4v*)(&O[((size_t)sg * N + i) * 64 + gl * 4]) = o;
        *(float4v*)(&ws[OF_MEAN + ((size_t)sg * N + i) * 64 + gl * 4]) = mn;
    }
    if (lane == 0) Lg[(size_t)sg * N + i] = lp - accL;
}

__device__ __forceinline__ void pool_role(int b, const void* __restrict__ efp,
                                          const void* __restrict__ efn,
                                          const uint32_t* __restrict__ iws,
                                          uint32_t fB, float* __restrict__ ws){
    int wid = threadIdx.x >> 6, lane = threadIdx.x & 63;
    int gw = b * 4 + wid;
    int g = gw / N, i = gw - g * N;
    const void* ef = (g < 2) ? efp : efn;
    uint32_t cnt = iws[OI_CUR + (size_t)g * N + i];
    if (cnt > (uint32_t)PAYC) cnt = PAYC;
    const uint32_t* Pay = iws + OI_PAY + ((size_t)g * N + i) * PAYC;
    int f = lane & 31, h = lane >> 5;
    float m = 0.f;
    uint32_t p = h;
    if (fB){
        const float* E = (const float*)ef;
        for (; p + 2 < cnt; p += 4){
            uint32_t e0 = Pay[p] & 0x3FFFFu, e1 = Pay[p + 2] & 0x3FFFFu;
            m = fmaxf(m, fmaxf(E[(size_t)e0 * 32 + f], E[(size_t)e1 * 32 + f]));
        }
        for (; p < cnt; p += 2)
            m = fmaxf(m, E[(size_t)(Pay[p] & 0x3FFFFu) * 32 + f]);
    } else {
        const bf* E = (const bf*)ef;
        for (; p + 2 < cnt; p += 4){
            uint32_t e0 = Pay[p] & 0x3FFFFu, e1 = Pay[p + 2] & 0x3FFFFu;
            m = fmaxf(m, fmaxf(b2f(E[(size_t)e0 * 32 + f]), b2f(E[(size_t)e1 * 32 + f])));
        }
        for (; p < cnt; p += 2)
            m = fmaxf(m, b2f(E[(size_t)(Pay[p] & 0x3FFFFu) * 32 + f]));
    }
    m = fmaxf(m, __shfl_xor(m, 32, 64));
    m = sane(m);
    float ss = m * m;
    ss += __shfl_xor(ss, 16, 64); ss += __shfl_xor(ss, 8, 64);
    ss += __shfl_xor(ss, 4, 64);  ss += __shfl_xor(ss, 2, 64);
    ss += __shfl_xor(ss, 1, 64);
    float r = m / fmaxf(sqrtf(ss), 1e-12f);
    if (lane < 32) ws[OF_POOL + ((size_t)g * N + i) * 32 + f] = sane(r);
}

__global__ void mega_kernel(const void* __restrict__ x1, const void* __restrict__ x2,
                            const void* __restrict__ efp, const void* __restrict__ efn,
                            const uint32_t* __restrict__ iws,
                            const float* __restrict__ ws_ro, float* __restrict__ ws){
    int b = blockIdx.x;
    const uint32_t* flags = iws + OI_FLAG;
    if (b < 3072) meancorr_role(b, x1, x2, flags[0], iws, ws_ro, ws,
                                ws + OF_O, ws + OF_L);
    else          pool_role(b - 3072, efp, efn, iws, flags[1], ws);
}

// ---- K4: O/L (pre-reduced) -> @Wo+bo -> +mean -> concat -> @weight+bias -> L2
__global__ void final_kernel(const void* __restrict__ x1, const void* __restrict__ x2,
                             const uint32_t* __restrict__ iws,
                             const float* __restrict__ ws, void* __restrict__ outv){
    uint32_t fA = iws[OI_FLAG + 0];
    int wid = threadIdx.x >> 6, c = threadIdx.x & 63;
    int i = blockIdx.x * 4 + wid;
    __shared__ float feat[4][384];
    __shared__ float onrm[4][64];
    for (int s = 0; s < 2; ++s){
        float osum = ws[OF_O + ((size_t)s * N + i) * 64 + c];
        float lsum = ws[OF_L + (size_t)s * N + i];
        onrm[wid][c] = sane(osum / fmaxf(lsum, 1e-20f));
        __syncthreads();
        const float* Wo = ws + OF_WO + (size_t)s * 4096;
        float attn = ws[OF_BO + s * 64 + c];
        #pragma unroll 8
        for (int d = 0; d < 64; ++d) attn += onrm[wid][d] * Wo[d * 64 + c];
        feat[wid][s * 64 + c] = sane(ws[OF_MEAN + (size_t)s * NF + (size_t)i * 64 + c] + attn);
        __syncthreads();
    }
    feat[wid][128 + c] = sane(ldf(x1, (size_t)i * 64 + c, fA));
    feat[wid][192 + c] = sane(ldf(x2, (size_t)i * 64 + c, fA));
    {
        int g0 = c >> 5, f = c & 31;
        feat[wid][256 + c] = ws[OF_POOL + ((size_t)g0 * N + i) * 32 + f];
        feat[wid][320 + c] = ws[OF_POOL + ((size_t)(2 + g0) * N + i) * 32 + f];
    }
    __syncthreads();
    float acc = ws[OF_BF + c];
    #pragma unroll 8
    for (int k = 0; k < 384; ++k) acc += feat[wid][k] * ws[OF_WF + (size_t)k * 64 + c];
    acc = sane(acc);
    float ss = acc * acc;
    ss += __shfl_xor(ss, 32, 64); ss += __shfl_xor(ss, 16, 64); ss += __shfl_xor(ss, 8, 64);
    ss += __shfl_xor(ss, 4, 64);  ss += __shfl_xor(ss, 2, 64);  ss += __shfl_xor(ss, 1, 64);
    float r = acc / fmaxf(sqrtf(ss), 1e-12f);
    if (fA) ((float*)outv)[(size_t)i * 64 + c] = r;
    else    ((bf*)outv)[(size_t)i * 64 + c] = __float2bfloat16(r);
}

extern "C" void kernel_launch(void* const* d_in, const int* in_sizes, int n_in,
                              void* d_out, int out_size, void* d_ws, size_t ws_size,
                              hipStream_t stream){
    const int* eip = (const int*)d_in[2];
    const int* ein = (const int*)d_in[3];

    float* ws = (float*)d_ws;
    uint32_t* iws = (uint32_t*)(ws + F_TOTAL);

    // 1) QKV GEMV || Wo/final staging || flags || counter-zero (no memsets)
    qkv_stage_kernel<<<dim3(9216 + 129 + 1 + 96), 256, 0, stream>>>(
        d_in[0], d_in[1],
        d_in[8],  d_in[10], d_in[12], d_in[16], d_in[18], d_in[20],
        d_in[9],  d_in[11], d_in[13], d_in[17], d_in[19], d_in[21],
        d_in[14], d_in[15], d_in[22], d_in[23],
        d_in[6],  d_in[7],  d_in[4],
        iws, ws);
    // 2) bucket fill (768, atomics, first) || dense MFMA attention (1536)
    attn_fill_kernel<<<dim3(768 + 1536), 256, 0, stream>>>(eip, ein, iws, ws, ws);
    // 3) merged mean+corr (3072, walks adjacency once) || pool (6144)
    mega_kernel<<<dim3(3072 + 6144), 256, 0, stream>>>(d_in[0], d_in[1], d_in[4], d_in[5],
                                                       iws, ws, ws);
    // 4) epilogue (reads pre-reduced O/L)
    final_kernel<<<dim3(N / 4), 256, 0, stream>>>(d_in[0], d_in[1], iws, ws, d_out);
}